// Round 1
// baseline (856.277 us; speedup 1.0000x reference)
//
#include <hip/hip_runtime.h>
#include <cstdint>
#include <cstddef>

#define ALPHA 1.702f
#define LIMIT 7.0f

// Problem dims (B=2, T=1024 -> N=2048 tokens)
#define NTOK 2048
#define HDIM 2048
#define IDIM 2048
#define I2   4096
#define NEXP 8

typedef float f32x4 __attribute__((ext_vector_type(4)));
typedef short bf16x8 __attribute__((ext_vector_type(8)));
typedef unsigned short u16;

__device__ __forceinline__ u16 f2bf(float f) {
  unsigned u = __float_as_uint(f);
  u += 0x7fffu + ((u >> 16) & 1u);   // round-to-nearest-even
  return (u16)(u >> 16);
}

__device__ __forceinline__ void gload_lds16(const void* g, void* l) {
  __builtin_amdgcn_global_load_lds(
      (const __attribute__((address_space(1))) void*)g,
      (__attribute__((address_space(3))) void*)l, 16, 0, 0);
}

// ---------------- x: fp32 -> bf16 straight convert ----------------
__global__ __launch_bounds__(256) void k_cvt(const float* __restrict__ in,
                                             u16* __restrict__ out) {
  int i = blockIdx.x * blockDim.x + threadIdx.x;   // each thread: 8 elems
  const float4* p = (const float4*)in + (size_t)i * 2;
  float4 a = p[0], b = p[1];
  union { u16 s[8]; uint4 v; } o;
  o.s[0] = f2bf(a.x); o.s[1] = f2bf(a.y); o.s[2] = f2bf(a.z); o.s[3] = f2bf(a.w);
  o.s[4] = f2bf(b.x); o.s[5] = f2bf(b.y); o.s[6] = f2bf(b.z); o.s[7] = f2bf(b.w);
  ((uint4*)out)[i] = o.v;
}

// ------------- transpose + convert: in (R,C) fp32 -> out (C,R) bf16 -------------
// blockIdx.z = expert (matrix stride R*C both sides)
__global__ __launch_bounds__(256) void k_tc(const float* __restrict__ in,
                                            u16* __restrict__ out, int R, int C) {
  __shared__ float tile[32][33];
  const size_t mo = (size_t)blockIdx.z * R * C;
  const float* ip = in + mo;
  u16* op = out + mo;
  int c0 = blockIdx.x * 32, r0 = blockIdx.y * 32;
  int t = threadIdx.x;
  int tr = t >> 3, tc = (t & 7) * 4;
  float4 v = *(const float4*)&ip[(size_t)(r0 + tr) * C + c0 + tc];
  tile[tr][tc] = v.x; tile[tr][tc + 1] = v.y;
  tile[tr][tc + 2] = v.z; tile[tr][tc + 3] = v.w;
  __syncthreads();
  ushort4 o;
  o.x = f2bf(tile[tc + 0][tr]);
  o.y = f2bf(tile[tc + 1][tr]);
  o.z = f2bf(tile[tc + 2][tr]);
  o.w = f2bf(tile[tc + 3][tr]);
  *(ushort4*)&op[(size_t)(c0 + tr) * R + r0 + tc] = o;
}

// ---------------- GEMM1: gate_up + activation + rw fold ----------------
// A = xbf (N,K=H) row-major; B = w1t[e] (4096, K=H) row-major (pre-transposed)
// inter[e][n][j] = rw[n,e] * (up+1)*gate*sigmoid(alpha*gate),  j = d/2
__global__ __launch_bounds__(256) void k_gemm1(const u16* __restrict__ xbf,
                                               const u16* __restrict__ w1t,
                                               const float* __restrict__ gub,
                                               const float* __restrict__ rw,
                                               u16* __restrict__ inter) {
  __shared__ __align__(16) u16 As[128 * 32];
  __shared__ __align__(16) u16 Bs[128 * 32];
  const int tid = threadIdx.x;
  const int lane = tid & 63, wid = tid >> 6;
  const int wr = wid >> 1, wc = wid & 1;
  const int row0 = blockIdx.x * 128;
  const int col0 = blockIdx.y * 128;
  const int e = blockIdx.z;
  const u16* A = xbf;
  const u16* B = w1t + (size_t)e * I2 * HDIM;

  f32x4 zero = {0.f, 0.f, 0.f, 0.f};
  f32x4 acc[4][4];
#pragma unroll
  for (int m = 0; m < 4; m++)
#pragma unroll
    for (int n = 0; n < 4; n++) acc[m][n] = zero;

  const int kb = (lane >> 4) * 8;
  const int rrow = lane & 15;

  for (int k0 = 0; k0 < HDIM; k0 += 32) {
#pragma unroll
    for (int i = 0; i < 2; i++) {
      int cb = wid * 128 + i * 64;     // chunk base for this wave/instr
      int ch = cb + lane;              // this lane's 16B chunk
      gload_lds16(A + (size_t)(row0 + (ch >> 2)) * HDIM + k0 + (ch & 3) * 8, &As[cb * 8]);
      gload_lds16(B + (size_t)(col0 + (ch >> 2)) * HDIM + k0 + (ch & 3) * 8, &Bs[cb * 8]);
    }
    __syncthreads();
    bf16x8 a[4], b[4];
#pragma unroll
    for (int m = 0; m < 4; m++)
      a[m] = *(const bf16x8*)&As[(wr * 64 + m * 16 + rrow) * 32 + kb];
#pragma unroll
    for (int n = 0; n < 4; n++)
      b[n] = *(const bf16x8*)&Bs[(wc * 64 + n * 16 + rrow) * 32 + kb];
#pragma unroll
    for (int m = 0; m < 4; m++)
#pragma unroll
      for (int n = 0; n < 4; n++)
        acc[m][n] = __builtin_amdgcn_mfma_f32_16x16x32_bf16(a[m], b[n], acc[m][n], 0, 0, 0);
    __syncthreads();
  }

  // epilogue: bias, pair (even=gate, odd=up) via shfl, activation, rw fold
  const float* bias = gub + (size_t)e * I2;
  u16* ip = inter + (size_t)e * NTOK * IDIM;
  float bv[4];
  int cols[4];
#pragma unroll
  for (int n = 0; n < 4; n++) {
    cols[n] = col0 + wc * 64 + n * 16 + (lane & 15);
    bv[n] = bias[cols[n]];
  }
#pragma unroll
  for (int m = 0; m < 4; m++) {
#pragma unroll
    for (int r = 0; r < 4; r++) {
      int row = row0 + wr * 64 + m * 16 + (lane >> 4) * 4 + r;
      float w = rw[row * NEXP + e];
#pragma unroll
      for (int n = 0; n < 4; n++) {
        float gu = acc[m][n][r] + bv[n];
        float pg = __shfl_xor(gu, 1);
        float gate = (lane & 1) ? pg : gu;
        float up   = (lane & 1) ? gu : pg;
        gate = fminf(gate, LIMIT);
        up = fminf(fmaxf(up, -LIMIT), LIMIT);
        float glu = gate / (1.f + __expf(-ALPHA * gate));
        float val = (up + 1.f) * glu * w;
        if (!(lane & 1))
          ip[(size_t)row * IDIM + (cols[n] >> 1)] = f2bf(val);
      }
    }
  }
}

// ---------------- GEMM2: out[n,h] = sum_e sum_i inter'[e,n,i]*W2t[e,h,i] + bias term ----------------
__global__ __launch_bounds__(256) void k_gemm2(const u16* __restrict__ inter,
                                               const u16* __restrict__ w2t,
                                               const float* __restrict__ dbias,
                                               const float* __restrict__ rw,
                                               float* __restrict__ out) {
  __shared__ __align__(16) u16 As[128 * 32];
  __shared__ __align__(16) u16 Bs[128 * 32];
  const int tid = threadIdx.x;
  const int lane = tid & 63, wid = tid >> 6;
  const int wr = wid >> 1, wc = wid & 1;
  const int row0 = blockIdx.x * 128;
  const int col0 = blockIdx.y * 128;

  f32x4 zero = {0.f, 0.f, 0.f, 0.f};
  f32x4 acc[4][4];
#pragma unroll
  for (int m = 0; m < 4; m++)
#pragma unroll
    for (int n = 0; n < 4; n++) acc[m][n] = zero;

  const int kb = (lane >> 4) * 8;
  const int rrow = lane & 15;

  for (int e = 0; e < NEXP; e++) {
    const u16* A = inter + (size_t)e * NTOK * IDIM;
    const u16* B = w2t + (size_t)e * HDIM * IDIM;
    for (int k0 = 0; k0 < IDIM; k0 += 32) {
#pragma unroll
      for (int i = 0; i < 2; i++) {
        int cb = wid * 128 + i * 64;
        int ch = cb + lane;
        gload_lds16(A + (size_t)(row0 + (ch >> 2)) * IDIM + k0 + (ch & 3) * 8, &As[cb * 8]);
        gload_lds16(B + (size_t)(col0 + (ch >> 2)) * IDIM + k0 + (ch & 3) * 8, &Bs[cb * 8]);
      }
      __syncthreads();
      bf16x8 a[4], b[4];
#pragma unroll
      for (int m = 0; m < 4; m++)
        a[m] = *(const bf16x8*)&As[(wr * 64 + m * 16 + rrow) * 32 + kb];
#pragma unroll
      for (int n = 0; n < 4; n++)
        b[n] = *(const bf16x8*)&Bs[(wc * 64 + n * 16 + rrow) * 32 + kb];
#pragma unroll
      for (int m = 0; m < 4; m++)
#pragma unroll
        for (int n = 0; n < 4; n++)
          acc[m][n] = __builtin_amdgcn_mfma_f32_16x16x32_bf16(a[m], b[n], acc[m][n], 0, 0, 0);
      __syncthreads();
    }
  }

  // epilogue: + sum_e rw[n,e]*down_bias[e,h]
  int cols[4];
  float dbv[4][NEXP];
#pragma unroll
  for (int n = 0; n < 4; n++) {
    cols[n] = col0 + wc * 64 + n * 16 + (lane & 15);
#pragma unroll
    for (int e = 0; e < NEXP; e++) dbv[n][e] = dbias[(size_t)e * HDIM + cols[n]];
  }
#pragma unroll
  for (int m = 0; m < 4; m++) {
#pragma unroll
    for (int r = 0; r < 4; r++) {
      int row = row0 + wr * 64 + m * 16 + (lane >> 4) * 4 + r;
      float4 r1 = *(const float4*)&rw[row * NEXP];
      float4 r2 = *(const float4*)&rw[row * NEXP + 4];
      float rv[8] = {r1.x, r1.y, r1.z, r1.w, r2.x, r2.y, r2.z, r2.w};
#pragma unroll
      for (int n = 0; n < 4; n++) {
        float bt = 0.f;
#pragma unroll
        for (int e = 0; e < NEXP; e++) bt += rv[e] * dbv[n][e];
        out[(size_t)row * HDIM + cols[n]] = acc[m][n][r] + bt;
      }
    }
  }
}

extern "C" void kernel_launch(void* const* d_in, const int* in_sizes, int n_in,
                              void* d_out, int out_size, void* d_ws, size_t ws_size,
                              hipStream_t stream) {
  const float* hs   = (const float*)d_in[0];  // (2,1024,2048)
  const float* rw   = (const float*)d_in[1];  // (2048,8)
  const float* gup  = (const float*)d_in[2];  // (8,2048,4096)
  const float* gupb = (const float*)d_in[3];  // (8,4096)
  const float* dwn  = (const float*)d_in[4];  // (8,2048,2048)
  const float* dwnb = (const float*)d_in[5];  // (8,2048)
  float* out = (float*)d_out;

  // workspace layout (bf16 as u16)
  u16* xbf   = (u16*)d_ws;                          //  4M elems =   8 MB
  u16* w1t   = xbf + (size_t)NTOK * HDIM;           // 64M elems = 128 MB
  u16* w2t   = w1t + (size_t)NEXP * I2 * HDIM;      // 32M elems =  64 MB
  u16* inter = w2t + (size_t)NEXP * HDIM * IDIM;    // 32M elems =  64 MB
  size_t need = ((size_t)NTOK * HDIM + (size_t)NEXP * I2 * HDIM +
                 (size_t)NEXP * HDIM * IDIM + (size_t)NEXP * NTOK * IDIM) * 2;
  if (ws_size < need) return;  // canary: zero output => ws too small, restructure

  k_cvt<<<(NTOK * HDIM) / (256 * 8), 256, 0, stream>>>(hs, xbf);

  dim3 g1(I2 / 32, HDIM / 32, NEXP);   // W1: (R=H, C=2I) -> (2I, H)
  k_tc<<<g1, 256, 0, stream>>>(gup, w1t, HDIM, I2);
  dim3 g2(HDIM / 32, IDIM / 32, NEXP); // W2: (R=I, C=H) -> (H, I)
  k_tc<<<g2, 256, 0, stream>>>(dwn, w2t, IDIM, HDIM);

  dim3 gg1(NTOK / 128, I2 / 128, NEXP);
  k_gemm1<<<gg1, 256, 0, stream>>>(xbf, w1t, gupb, rw, inter);

  dim3 gg2(NTOK / 128, HDIM / 128);
  k_gemm2<<<gg2, 256, 0, stream>>>(inter, w2t, dwnb, rw, out);
}

// Round 2
// 773.013 us; speedup vs baseline: 1.1077x; 1.1077x over previous
//
#include <hip/hip_runtime.h>
#include <cstdint>
#include <cstddef>

#define ALPHA 1.702f
#define LIMIT 7.0f

#define NTOK 2048
#define HDIM 2048
#define IDIM 2048
#define I2   4096
#define NEXP 8

typedef float f32x4 __attribute__((ext_vector_type(4)));
typedef short bf16x8 __attribute__((ext_vector_type(8)));
typedef unsigned short u16;

__device__ __forceinline__ u16 f2bf(float f) {
  unsigned u = __float_as_uint(f);
  u += 0x7fffu + ((u >> 16) & 1u);   // RNE
  return (u16)(u >> 16);
}

__device__ __forceinline__ void gload_lds16(const void* g, void* l) {
  __builtin_amdgcn_global_load_lds(
      (const __attribute__((address_space(1))) void*)g,
      (__attribute__((address_space(3))) void*)l, 16, 0, 0);
}

#define BARRIER() do { asm volatile("" ::: "memory"); __builtin_amdgcn_s_barrier(); __builtin_amdgcn_sched_barrier(0); } while (0)
#define LGKM0()   do { asm volatile("s_waitcnt lgkmcnt(0)" ::: "memory"); __builtin_amdgcn_sched_barrier(0); } while (0)
#define VMCNT(n)  asm volatile("s_waitcnt vmcnt(" #n ")" ::: "memory")

// ---------------- x: fp32 -> bf16 ----------------
__global__ __launch_bounds__(256) void k_cvt(const float* __restrict__ in,
                                             u16* __restrict__ out) {
  int i = blockIdx.x * blockDim.x + threadIdx.x;
  const float4* p = (const float4*)in + (size_t)i * 2;
  float4 a = p[0], b = p[1];
  union { u16 s[8]; uint4 v; } o;
  o.s[0] = f2bf(a.x); o.s[1] = f2bf(a.y); o.s[2] = f2bf(a.z); o.s[3] = f2bf(a.w);
  o.s[4] = f2bf(b.x); o.s[5] = f2bf(b.y); o.s[6] = f2bf(b.z); o.s[7] = f2bf(b.w);
  ((uint4*)out)[i] = o.v;
}

// ------------- transpose + convert: (R,C) fp32 -> (C,R) bf16 -------------
__global__ __launch_bounds__(256) void k_tc(const float* __restrict__ in,
                                            u16* __restrict__ out, int R, int C) {
  __shared__ float tile[32][33];
  const size_t mo = (size_t)blockIdx.z * R * C;
  const float* ip = in + mo;
  u16* op = out + mo;
  int c0 = blockIdx.x * 32, r0 = blockIdx.y * 32;
  int t = threadIdx.x;
  int tr = t >> 3, tc = (t & 7) * 4;
  float4 v = *(const float4*)&ip[(size_t)(r0 + tr) * C + c0 + tc];
  tile[tr][tc] = v.x; tile[tr][tc + 1] = v.y;
  tile[tr][tc + 2] = v.z; tile[tr][tc + 3] = v.w;
  __syncthreads();
  ushort4 o;
  o.x = f2bf(tile[tc + 0][tr]);
  o.y = f2bf(tile[tc + 1][tr]);
  o.z = f2bf(tile[tc + 2][tr]);
  o.w = f2bf(tile[tc + 3][tr]);
  *(ushort4*)&op[(size_t)(c0 + tr) * R + r0 + tc] = o;
}

// ---------------- GEMM1: 256x256 tile, BK=64, 8-wave 8-phase pipeline ----------------
// A = xbf (NTOK, HDIM); B = w1t[e] (I2, HDIM) row-major K-contiguous.
// LDS regions (16 KB each = 128 lds-rows x 64 bf16):
//   Als[buf*2+h]: A half h of K-tile in buf; lds row = wr*64 + (rowInWaveHalf)
//   Bls[buf*2+h]: B half h;                  lds row = wc*32 + (colInWaveHalf)
// XOR swizzle: 16B slot g stored at slot g ^ (ldsrow & 7)  (both-sides, rule 21).
#define MFMA_Q(mh, nh, bb) \
  _Pragma("unroll") for (int mm = 0; mm < 4; ++mm) \
  _Pragma("unroll") for (int nn = 0; nn < 2; ++nn) \
  _Pragma("unroll") for (int ks = 0; ks < 2; ++ks) \
    acc[(mh)*4+mm][(nh)*2+nn] = __builtin_amdgcn_mfma_f32_16x16x32_bf16( \
        a[mm][ks], (bb)[nn][ks], acc[(mh)*4+mm][(nh)*2+nn], 0, 0, 0);

__global__ __launch_bounds__(512, 2) void k_gemm1(const u16* __restrict__ xbf,
                                                  const u16* __restrict__ w1t,
                                                  const float* __restrict__ gub,
                                                  const float* __restrict__ rw,
                                                  u16* __restrict__ inter) {
  __shared__ __align__(16) u16 Als[4][128 * 64];
  __shared__ __align__(16) u16 Bls[4][128 * 64];

  // XCD swizzle (nwg=1024, 8 XCDs): XCD x gets logical ids [x*128, x*128+128)
  const int bid = (int)blockIdx.x;
  const int L = (bid & 7) * 128 + (bid >> 3);
  const int mtile = L & 7, ntile = (L >> 3) & 15, e = L >> 7; // each XCD = 1 expert
  const int row0 = mtile * 256, col0 = ntile * 256;
  const u16* A = xbf;
  const u16* B = w1t + (size_t)e * I2 * HDIM;

  const int tid = threadIdx.x;
  const int w = tid >> 6, lane = tid & 63;
  const int wr = w >> 2, wc = w & 3;           // 2 x 4 wave grid
  const int rrow = lane & 15, klane = lane >> 4;
  const int sA = (wr * 64 + rrow) * 64;
  const int sB = (wc * 32 + rrow) * 64;
  int kofs[2];
  kofs[0] = ((klane ^ (rrow & 7)) << 3);
  kofs[1] = (((4 + klane) ^ (rrow & 7)) << 3);

  // staging helpers: 2 x gload_lds16 per thread = one 16KB half-tile per call
  auto stA = [&](int reg, int h, int k0) {
#pragma unroll
    for (int j = 0; j < 2; ++j) {
      int c = (w * 2 + j) * 64 + lane;          // chunk 0..1023
      int r = c >> 3, gg = c & 7;
      int ksw = ((gg ^ (r & 7)) << 3);          // inverse-swizzled source k
      int R = ((r >> 6) << 7) + h * 64 + (r & 63);
      gload_lds16(A + (size_t)(row0 + R) * HDIM + k0 + ksw,
                  &Als[reg][(size_t)(w * 2 + j) * 512]);
    }
  };
  auto stB = [&](int reg, int h, int k0) {
#pragma unroll
    for (int j = 0; j < 2; ++j) {
      int c = (w * 2 + j) * 64 + lane;
      int r = c >> 3, gg = c & 7;
      int ksw = ((gg ^ (r & 7)) << 3);
      int C = ((r >> 5) << 6) + h * 32 + (r & 31);
      gload_lds16(B + (size_t)(col0 + C) * HDIM + k0 + ksw,
                  &Bls[reg][(size_t)(w * 2 + j) * 512]);
    }
  };

  f32x4 acc[8][4];
#pragma unroll
  for (int i = 0; i < 8; ++i)
#pragma unroll
    for (int j = 0; j < 4; ++j) acc[i][j] = (f32x4){0.f, 0.f, 0.f, 0.f};

  bf16x8 a[4][2], b0[2][2], b1[2][2];
  auto rdA = [&](int reg) {
#pragma unroll
    for (int mm = 0; mm < 4; ++mm)
#pragma unroll
      for (int ks = 0; ks < 2; ++ks)
        a[mm][ks] = *(const bf16x8*)&Als[reg][sA + mm * 1024 + kofs[ks]];
  };
  auto rdB0 = [&](int reg) {
#pragma unroll
    for (int nn = 0; nn < 2; ++nn)
#pragma unroll
      for (int ks = 0; ks < 2; ++ks)
        b0[nn][ks] = *(const bf16x8*)&Bls[reg][sB + nn * 1024 + kofs[ks]];
  };
  auto rdB1 = [&](int reg) {
#pragma unroll
    for (int nn = 0; nn < 2; ++nn)
#pragma unroll
      for (int ks = 0; ks < 2; ++ks)
        b1[nn][ks] = *(const bf16x8*)&Bls[reg][sB + nn * 1024 + kofs[ks]];
  };

  // prologue: stage tile0 fully + tile1 (Bh0,Bh1,Ah0); order matters for vmcnt
  stB(0, 0, 0); stB(1, 1, 0); stA(0, 0, 0); stA(1, 1, 0);
  stB(2, 0, 64); stB(3, 1, 64); stA(2, 0, 64);
  VMCNT(8);
  BARRIER();

  for (int i = 0; i < 16; ++i) {
    const int t = 2 * i;
    const int kA1 = (t + 1) * 64;                           // always valid
    const int kN0 = (t + 2 < 32 ? t + 2 : 31) * 64;         // clamped tail
    const int kN1 = (t + 3 < 32 ? t + 3 : 31) * 64;

    // ph0: q(0,0) buf0
    rdA(0); rdB0(0);
    stA(3, 1, kA1);                 // A-h1(buf1) <- tile t+1
    BARRIER(); LGKM0();
    __builtin_amdgcn_s_setprio(1); MFMA_Q(0, 0, b0); __builtin_amdgcn_s_setprio(0);
    BARRIER();

    // ph1: q(0,1) buf0
    rdB1(1);
    stB(0, 0, kN0);                 // B-h0(buf0) <- t+2
    BARRIER(); LGKM0();
    __builtin_amdgcn_s_setprio(1); MFMA_Q(0, 1, b1); __builtin_amdgcn_s_setprio(0);
    VMCNT(10);
    BARRIER();

    // ph2: q(1,0) buf0
    rdA(1);
    stB(1, 1, kN0);                 // B-h1(buf0) <- t+2
    BARRIER(); LGKM0();
    __builtin_amdgcn_s_setprio(1); MFMA_Q(1, 0, b0); __builtin_amdgcn_s_setprio(0);
    BARRIER();

    // ph3: q(1,1) buf0
    stA(0, 0, kN0);                 // A-h0(buf0) <- t+2
    BARRIER(); LGKM0();
    __builtin_amdgcn_s_setprio(1); MFMA_Q(1, 1, b1); __builtin_amdgcn_s_setprio(0);
    VMCNT(8);
    BARRIER();

    // ph4: q(0,0) buf1
    rdA(2); rdB0(2);
    stA(1, 1, kN0);                 // A-h1(buf0) <- t+2
    BARRIER(); LGKM0();
    __builtin_amdgcn_s_setprio(1); MFMA_Q(0, 0, b0); __builtin_amdgcn_s_setprio(0);
    BARRIER();

    // ph5: q(0,1) buf1
    rdB1(3);
    stB(2, 0, kN1);                 // B-h0(buf1) <- t+3
    BARRIER(); LGKM0();
    __builtin_amdgcn_s_setprio(1); MFMA_Q(0, 1, b1); __builtin_amdgcn_s_setprio(0);
    VMCNT(10);
    BARRIER();

    // ph6: q(1,0) buf1
    rdA(3);
    stB(3, 1, kN1);                 // B-h1(buf1) <- t+3
    BARRIER(); LGKM0();
    __builtin_amdgcn_s_setprio(1); MFMA_Q(1, 0, b0); __builtin_amdgcn_s_setprio(0);
    BARRIER();

    // ph7: q(1,1) buf1
    stA(2, 0, kN1);                 // A-h0(buf1) <- t+3
    BARRIER(); LGKM0();
    __builtin_amdgcn_s_setprio(1); MFMA_Q(1, 1, b1); __builtin_amdgcn_s_setprio(0);
    VMCNT(8);
    BARRIER();
  }

  // epilogue: bias, gate/up pairing via shfl, activation, rw fold, bf16 store
  const float* bias = gub + (size_t)e * I2;
  u16* ip = inter + (size_t)e * NTOK * IDIM;
#pragma unroll
  for (int ai = 0; ai < 8; ++ai) {
    const int mh = ai >> 2, mm = ai & 3;
#pragma unroll
    for (int bj = 0; bj < 4; ++bj) {
      const int nh = bj >> 1, nn = bj & 1;
      const int col = col0 + wc * 64 + nh * 32 + nn * 16 + rrow;
      const float bv = bias[col];
#pragma unroll
      for (int r = 0; r < 4; ++r) {
        const int row = row0 + wr * 128 + mh * 64 + mm * 16 + klane * 4 + r;
        float gu = acc[ai][bj][r] + bv;
        float pg = __shfl_xor(gu, 1);
        float gate = (lane & 1) ? pg : gu;
        float up   = (lane & 1) ? gu : pg;
        gate = fminf(gate, LIMIT);
        up = fminf(fmaxf(up, -LIMIT), LIMIT);
        float glu = gate / (1.f + __expf(-ALPHA * gate));
        float val = (up + 1.f) * glu * rw[row * NEXP + e];
        if (!(lane & 1)) ip[(size_t)row * IDIM + (col >> 1)] = f2bf(val);
      }
    }
  }
}

// ---------------- GEMM2 (unchanged 128^2 structure this round) ----------------
__global__ __launch_bounds__(256) void k_gemm2(const u16* __restrict__ inter,
                                               const u16* __restrict__ w2t,
                                               const float* __restrict__ dbias,
                                               const float* __restrict__ rw,
                                               float* __restrict__ out) {
  __shared__ __align__(16) u16 As[128 * 32];
  __shared__ __align__(16) u16 Bs[128 * 32];
  const int tid = threadIdx.x;
  const int lane = tid & 63, wid = tid >> 6;
  const int wr = wid >> 1, wc = wid & 1;
  const int row0 = blockIdx.x * 128;
  const int col0 = blockIdx.y * 128;

  f32x4 zero = {0.f, 0.f, 0.f, 0.f};
  f32x4 acc[4][4];
#pragma unroll
  for (int m = 0; m < 4; m++)
#pragma unroll
    for (int n = 0; n < 4; n++) acc[m][n] = zero;

  const int kb = (lane >> 4) * 8;
  const int rrow = lane & 15;

  for (int e = 0; e < NEXP; e++) {
    const u16* A = inter + (size_t)e * NTOK * IDIM;
    const u16* B = w2t + (size_t)e * HDIM * IDIM;
    for (int k0 = 0; k0 < IDIM; k0 += 32) {
#pragma unroll
      for (int i = 0; i < 2; i++) {
        int cb = wid * 128 + i * 64;
        int ch = cb + lane;
        gload_lds16(A + (size_t)(row0 + (ch >> 2)) * IDIM + k0 + (ch & 3) * 8, &As[cb * 8]);
        gload_lds16(B + (size_t)(col0 + (ch >> 2)) * IDIM + k0 + (ch & 3) * 8, &Bs[cb * 8]);
      }
      __syncthreads();
      bf16x8 a[4], b[4];
#pragma unroll
      for (int m = 0; m < 4; m++)
        a[m] = *(const bf16x8*)&As[(wr * 64 + m * 16 + rrow) * 32 + kb];
#pragma unroll
      for (int n = 0; n < 4; n++)
        b[n] = *(const bf16x8*)&Bs[(wc * 64 + n * 16 + rrow) * 32 + kb];
#pragma unroll
      for (int m = 0; m < 4; m++)
#pragma unroll
        for (int n = 0; n < 4; n++)
          acc[m][n] = __builtin_amdgcn_mfma_f32_16x16x32_bf16(a[m], b[n], acc[m][n], 0, 0, 0);
      __syncthreads();
    }
  }

  int cols[4];
  float dbv[4][NEXP];
#pragma unroll
  for (int n = 0; n < 4; n++) {
    cols[n] = col0 + wc * 64 + n * 16 + (lane & 15);
#pragma unroll
    for (int e = 0; e < NEXP; e++) dbv[n][e] = dbias[(size_t)e * HDIM + cols[n]];
  }
#pragma unroll
  for (int m = 0; m < 4; m++) {
#pragma unroll
    for (int r = 0; r < 4; r++) {
      int row = row0 + wr * 64 + m * 16 + (lane >> 4) * 4 + r;
      float4 r1 = *(const float4*)&rw[row * NEXP];
      float4 r2 = *(const float4*)&rw[row * NEXP + 4];
      float rv[8] = {r1.x, r1.y, r1.z, r1.w, r2.x, r2.y, r2.z, r2.w};
#pragma unroll
      for (int n = 0; n < 4; n++) {
        float bt = 0.f;
#pragma unroll
        for (int e = 0; e < NEXP; e++) bt += rv[e] * dbv[n][e];
        out[(size_t)row * HDIM + cols[n]] = acc[m][n][r] + bt;
      }
    }
  }
}

extern "C" void kernel_launch(void* const* d_in, const int* in_sizes, int n_in,
                              void* d_out, int out_size, void* d_ws, size_t ws_size,
                              hipStream_t stream) {
  const float* hs   = (const float*)d_in[0];
  const float* rw   = (const float*)d_in[1];
  const float* gup  = (const float*)d_in[2];
  const float* gupb = (const float*)d_in[3];
  const float* dwn  = (const float*)d_in[4];
  const float* dwnb = (const float*)d_in[5];
  float* out = (float*)d_out;

  u16* xbf   = (u16*)d_ws;
  u16* w1t   = xbf + (size_t)NTOK * HDIM;
  u16* w2t   = w1t + (size_t)NEXP * I2 * HDIM;
  u16* inter = w2t + (size_t)NEXP * HDIM * IDIM;
  size_t need = ((size_t)NTOK * HDIM + (size_t)NEXP * I2 * HDIM +
                 (size_t)NEXP * HDIM * IDIM + (size_t)NEXP * NTOK * IDIM) * 2;
  if (ws_size < need) return;

  k_cvt<<<(NTOK * HDIM) / (256 * 8), 256, 0, stream>>>(hs, xbf);

  dim3 g1(I2 / 32, HDIM / 32, NEXP);
  k_tc<<<g1, 256, 0, stream>>>(gup, w1t, HDIM, I2);
  dim3 g2(HDIM / 32, IDIM / 32, NEXP);
  k_tc<<<g2, 256, 0, stream>>>(dwn, w2t, IDIM, HDIM);

  k_gemm1<<<dim3(1024), 512, 0, stream>>>(xbf, w1t, gupb, rw, inter);

  dim3 gg2(NTOK / 128, HDIM / 128);
  k_gemm2<<<gg2, 256, 0, stream>>>(inter, w2t, dwnb, rw, out);
}

// Round 4
// 565.159 us; speedup vs baseline: 1.5151x; 1.3678x over previous
//
#include <hip/hip_runtime.h>
#include <cstdint>
#include <cstddef>

#define ALPHA 1.702f
#define LIMIT 7.0f

#define NTOK 2048
#define HDIM 2048
#define IDIM 2048
#define I2   4096
#define NEXP 8

typedef float f32x4 __attribute__((ext_vector_type(4)));
typedef short bf16x8 __attribute__((ext_vector_type(8)));
typedef unsigned short u16;

__device__ __forceinline__ u16 f2bf(float f) {
  unsigned u = __float_as_uint(f);
  u += 0x7fffu + ((u >> 16) & 1u);   // RNE
  return (u16)(u >> 16);
}

__device__ __forceinline__ void gload_lds16(const void* g, void* l) {
  __builtin_amdgcn_global_load_lds(
      (const __attribute__((address_space(1))) void*)g,
      (__attribute__((address_space(3))) void*)l, 16, 0, 0);
}

#define BARRIER() do { asm volatile("" ::: "memory"); __builtin_amdgcn_s_barrier(); __builtin_amdgcn_sched_barrier(0); } while (0)
#define LGKM0()   do { asm volatile("s_waitcnt lgkmcnt(0)" ::: "memory"); __builtin_amdgcn_sched_barrier(0); } while (0)
#define VMCNT(n)  asm volatile("s_waitcnt vmcnt(" #n ")" ::: "memory")

// ---------------- x: fp32 -> bf16 ----------------
__global__ __launch_bounds__(256) void k_cvt(const float* __restrict__ in,
                                             u16* __restrict__ out) {
  int i = blockIdx.x * blockDim.x + threadIdx.x;
  const float4* p = (const float4*)in + (size_t)i * 2;
  float4 a = p[0], b = p[1];
  union { u16 s[8]; uint4 v; } o;
  o.s[0] = f2bf(a.x); o.s[1] = f2bf(a.y); o.s[2] = f2bf(a.z); o.s[3] = f2bf(a.w);
  o.s[4] = f2bf(b.x); o.s[5] = f2bf(b.y); o.s[6] = f2bf(b.z); o.s[7] = f2bf(b.w);
  ((uint4*)out)[i] = o.v;
}

// ------------- transpose + convert: (R,C) fp32 -> (C,R) bf16 (round-2 verified 32x32) -------------
__global__ __launch_bounds__(256) void k_tc(const float* __restrict__ in,
                                            u16* __restrict__ out, int R, int C) {
  __shared__ float tile[32][33];
  const size_t mo = (size_t)blockIdx.z * R * C;
  const float* ip = in + mo;
  u16* op = out + mo;
  int c0 = blockIdx.x * 32, r0 = blockIdx.y * 32;
  int t = threadIdx.x;
  int tr = t >> 3, tc = (t & 7) * 4;
  float4 v = *(const float4*)&ip[(size_t)(r0 + tr) * C + c0 + tc];
  tile[tr][tc] = v.x; tile[tr][tc + 1] = v.y;
  tile[tr][tc + 2] = v.z; tile[tr][tc + 3] = v.w;
  __syncthreads();
  ushort4 o;
  o.x = f2bf(tile[tc + 0][tr]);
  o.y = f2bf(tile[tc + 1][tr]);
  o.z = f2bf(tile[tc + 2][tr]);
  o.w = f2bf(tile[tc + 3][tr]);
  *(ushort4*)&op[(size_t)(c0 + tr) * R + r0 + tc] = o;
}

// ======================= 256x256 8-wave 8-phase GEMM core =======================
#define MFMA_Q(mh, nh, bb) \
  _Pragma("unroll") for (int mm = 0; mm < 4; ++mm) \
  _Pragma("unroll") for (int nn = 0; nn < 2; ++nn) \
  _Pragma("unroll") for (int ks = 0; ks < 2; ++ks) \
    acc[(mh)*4+mm][(nh)*2+nn] = __builtin_amdgcn_mfma_f32_16x16x32_bf16( \
        a[mm][ks], (bb)[nn][ks], acc[(mh)*4+mm][(nh)*2+nn], 0, 0, 0);

// ---------------- GEMM1: gate_up + activation + rw fold ----------------
__global__ __launch_bounds__(512, 2) void k_gemm1(const u16* __restrict__ xbf,
                                                  const u16* __restrict__ w1t,
                                                  const float* __restrict__ gub,
                                                  const float* __restrict__ rw,
                                                  u16* __restrict__ inter) {
  __shared__ __align__(16) u16 Als[4][128 * 64];
  __shared__ __align__(16) u16 Bls[4][128 * 64];

  const int bid = (int)blockIdx.x;
  const int L = (bid & 7) * 128 + (bid >> 3);
  const int mtile = L & 7, ntile = (L >> 3) & 15, e = L >> 7;
  const int row0 = mtile * 256, col0 = ntile * 256;
  const u16* A = xbf;
  const u16* B = w1t + (size_t)e * I2 * HDIM;

  const int tid = threadIdx.x;
  const int w = tid >> 6, lane = tid & 63;
  const int wr = w >> 2, wc = w & 3;
  const int rrow = lane & 15, klane = lane >> 4;
  const int sA = (wr * 64 + rrow) * 64;
  const int sB = (wc * 32 + rrow) * 64;
  int kofs[2];
  kofs[0] = ((klane ^ (rrow & 7)) << 3);
  kofs[1] = (((4 + klane) ^ (rrow & 7)) << 3);

  auto stA = [&](int reg, int h, int k0) {
#pragma unroll
    for (int j = 0; j < 2; ++j) {
      int c = (w * 2 + j) * 64 + lane;
      int r = c >> 3, gg = c & 7;
      int ksw = ((gg ^ (r & 7)) << 3);
      int R = ((r >> 6) << 7) + h * 64 + (r & 63);
      gload_lds16(A + (size_t)(row0 + R) * HDIM + k0 + ksw,
                  &Als[reg][(size_t)(w * 2 + j) * 512]);
    }
  };
  auto stB = [&](int reg, int h, int k0) {
#pragma unroll
    for (int j = 0; j < 2; ++j) {
      int c = (w * 2 + j) * 64 + lane;
      int r = c >> 3, gg = c & 7;
      int ksw = ((gg ^ (r & 7)) << 3);
      int C = ((r >> 5) << 6) + h * 32 + (r & 31);
      gload_lds16(B + (size_t)(col0 + C) * HDIM + k0 + ksw,
                  &Bls[reg][(size_t)(w * 2 + j) * 512]);
    }
  };

  f32x4 acc[8][4];
#pragma unroll
  for (int i = 0; i < 8; ++i)
#pragma unroll
    for (int j = 0; j < 4; ++j) acc[i][j] = (f32x4){0.f, 0.f, 0.f, 0.f};

  bf16x8 a[4][2], b0[2][2], b1[2][2];
  auto rdA = [&](int reg) {
#pragma unroll
    for (int mm = 0; mm < 4; ++mm)
#pragma unroll
      for (int ks = 0; ks < 2; ++ks)
        a[mm][ks] = *(const bf16x8*)&Als[reg][sA + mm * 1024 + kofs[ks]];
  };
  auto rdB0 = [&](int reg) {
#pragma unroll
    for (int nn = 0; nn < 2; ++nn)
#pragma unroll
      for (int ks = 0; ks < 2; ++ks)
        b0[nn][ks] = *(const bf16x8*)&Bls[reg][sB + nn * 1024 + kofs[ks]];
  };
  auto rdB1 = [&](int reg) {
#pragma unroll
    for (int nn = 0; nn < 2; ++nn)
#pragma unroll
      for (int ks = 0; ks < 2; ++ks)
        b1[nn][ks] = *(const bf16x8*)&Bls[reg][sB + nn * 1024 + kofs[ks]];
  };

  stB(0, 0, 0); stB(1, 1, 0); stA(0, 0, 0); stA(1, 1, 0);
  stB(2, 0, 64); stB(3, 1, 64); stA(2, 0, 64);
  VMCNT(8);
  BARRIER();

  for (int i = 0; i < 16; ++i) {
    const int t = 2 * i;
    const int kA1 = (t + 1) * 64;
    const int kN0 = (t + 2 < 32 ? t + 2 : 31) * 64;
    const int kN1 = (t + 3 < 32 ? t + 3 : 31) * 64;

    rdA(0); rdB0(0);
    stA(3, 1, kA1);
    BARRIER(); LGKM0();
    __builtin_amdgcn_s_setprio(1); MFMA_Q(0, 0, b0); __builtin_amdgcn_s_setprio(0);
    BARRIER();

    rdB1(1);
    stB(0, 0, kN0);
    BARRIER(); LGKM0();
    __builtin_amdgcn_s_setprio(1); MFMA_Q(0, 1, b1); __builtin_amdgcn_s_setprio(0);
    VMCNT(10);
    BARRIER();

    rdA(1);
    stB(1, 1, kN0);
    BARRIER(); LGKM0();
    __builtin_amdgcn_s_setprio(1); MFMA_Q(1, 0, b0); __builtin_amdgcn_s_setprio(0);
    BARRIER();

    stA(0, 0, kN0);
    BARRIER(); LGKM0();
    __builtin_amdgcn_s_setprio(1); MFMA_Q(1, 1, b1); __builtin_amdgcn_s_setprio(0);
    VMCNT(8);
    BARRIER();

    rdA(2); rdB0(2);
    stA(1, 1, kN0);
    BARRIER(); LGKM0();
    __builtin_amdgcn_s_setprio(1); MFMA_Q(0, 0, b0); __builtin_amdgcn_s_setprio(0);
    BARRIER();

    rdB1(3);
    stB(2, 0, kN1);
    BARRIER(); LGKM0();
    __builtin_amdgcn_s_setprio(1); MFMA_Q(0, 1, b1); __builtin_amdgcn_s_setprio(0);
    VMCNT(10);
    BARRIER();

    rdA(3);
    stB(3, 1, kN1);
    BARRIER(); LGKM0();
    __builtin_amdgcn_s_setprio(1); MFMA_Q(1, 0, b0); __builtin_amdgcn_s_setprio(0);
    BARRIER();

    stA(2, 0, kN1);
    BARRIER(); LGKM0();
    __builtin_amdgcn_s_setprio(1); MFMA_Q(1, 1, b1); __builtin_amdgcn_s_setprio(0);
    VMCNT(8);
    BARRIER();
  }

  const float* bias = gub + (size_t)e * I2;
  u16* ip = inter + (size_t)e * NTOK * IDIM;
#pragma unroll
  for (int ai = 0; ai < 8; ++ai) {
    const int mh = ai >> 2, mm = ai & 3;
#pragma unroll
    for (int bj = 0; bj < 4; ++bj) {
      const int nh = bj >> 1, nn = bj & 1;
      const int col = col0 + wc * 64 + nh * 32 + nn * 16 + rrow;
      const float bv = bias[col];
#pragma unroll
      for (int r = 0; r < 4; ++r) {
        const int row = row0 + wr * 128 + mh * 64 + mm * 16 + klane * 4 + r;
        float gu = acc[ai][bj][r] + bv;
        float pg = __shfl_xor(gu, 1);
        float gate = (lane & 1) ? pg : gu;
        float up   = (lane & 1) ? gu : pg;
        gate = fminf(gate, LIMIT);
        up = fminf(fmaxf(up, -LIMIT), LIMIT);
        float glu = gate / (1.f + __expf(-ALPHA * gate));
        float val = (up + 1.f) * glu * rw[row * NEXP + e];
        if (!(lane & 1)) ip[(size_t)row * IDIM + (col >> 1)] = f2bf(val);
      }
    }
  }
}

// ---------------- GEMM2: 256x256 8-phase, split-K=4 (2 experts per split) ----------------
__global__ __launch_bounds__(512, 2) void k_gemm2(const u16* __restrict__ inter,
                                                  const u16* __restrict__ w2t,
                                                  float* __restrict__ part) {
  __shared__ __align__(16) u16 Als[4][128 * 64];
  __shared__ __align__(16) u16 Bls[4][128 * 64];

  // 256 blocks: bijective XCD swizzle; L -> (mt, nt, split)
  const int bid = (int)blockIdx.x;
  const int L = (bid & 7) * 32 + (bid >> 3);
  const int mtile = L & 7, ntile = (L >> 3) & 7, sp = L >> 6;
  const int row0 = mtile * 256, col0 = ntile * 256;
  const int es = sp * 2;

  const int tid = threadIdx.x;
  const int w = tid >> 6, lane = tid & 63;
  const int wr = w >> 2, wc = w & 3;
  const int rrow = lane & 15, klane = lane >> 4;
  const int sA = (wr * 64 + rrow) * 64;
  const int sB = (wc * 32 + rrow) * 64;
  int kofs[2];
  kofs[0] = ((klane ^ (rrow & 7)) << 3);
  kofs[1] = (((4 + klane) ^ (rrow & 7)) << 3);

  // k0 in [0, 4096): expert = es + (k0>>11), intra-expert k = k0 & 2047
  auto stA = [&](int reg, int h, int k0) {
    const u16* Ab = inter + (size_t)(es + (k0 >> 11)) * NTOK * IDIM;
    const int kk = k0 & 2047;
#pragma unroll
    for (int j = 0; j < 2; ++j) {
      int c = (w * 2 + j) * 64 + lane;
      int r = c >> 3, gg = c & 7;
      int ksw = ((gg ^ (r & 7)) << 3);
      int R = ((r >> 6) << 7) + h * 64 + (r & 63);
      gload_lds16(Ab + (size_t)(row0 + R) * IDIM + kk + ksw,
                  &Als[reg][(size_t)(w * 2 + j) * 512]);
    }
  };
  auto stB = [&](int reg, int h, int k0) {
    const u16* Bb = w2t + (size_t)(es + (k0 >> 11)) * HDIM * IDIM;
    const int kk = k0 & 2047;
#pragma unroll
    for (int j = 0; j < 2; ++j) {
      int c = (w * 2 + j) * 64 + lane;
      int r = c >> 3, gg = c & 7;
      int ksw = ((gg ^ (r & 7)) << 3);
      int C = ((r >> 5) << 6) + h * 32 + (r & 31);
      gload_lds16(Bb + (size_t)(col0 + C) * IDIM + kk + ksw,
                  &Bls[reg][(size_t)(w * 2 + j) * 512]);
    }
  };

  f32x4 acc[8][4];
#pragma unroll
  for (int i = 0; i < 8; ++i)
#pragma unroll
    for (int j = 0; j < 4; ++j) acc[i][j] = (f32x4){0.f, 0.f, 0.f, 0.f};

  bf16x8 a[4][2], b0[2][2], b1[2][2];
  auto rdA = [&](int reg) {
#pragma unroll
    for (int mm = 0; mm < 4; ++mm)
#pragma unroll
      for (int ks = 0; ks < 2; ++ks)
        a[mm][ks] = *(const bf16x8*)&Als[reg][sA + mm * 1024 + kofs[ks]];
  };
  auto rdB0 = [&](int reg) {
#pragma unroll
    for (int nn = 0; nn < 2; ++nn)
#pragma unroll
      for (int ks = 0; ks < 2; ++ks)
        b0[nn][ks] = *(const bf16x8*)&Bls[reg][sB + nn * 1024 + kofs[ks]];
  };
  auto rdB1 = [&](int reg) {
#pragma unroll
    for (int nn = 0; nn < 2; ++nn)
#pragma unroll
      for (int ks = 0; ks < 2; ++ks)
        b1[nn][ks] = *(const bf16x8*)&Bls[reg][sB + nn * 1024 + kofs[ks]];
  };

  stB(0, 0, 0); stB(1, 1, 0); stA(0, 0, 0); stA(1, 1, 0);
  stB(2, 0, 64); stB(3, 1, 64); stA(2, 0, 64);
  VMCNT(8);
  BARRIER();

  for (int i = 0; i < 32; ++i) {               // 64 K-tiles, 2 per iter
    const int t = 2 * i;
    const int kA1 = (t + 1) * 64;
    const int kN0 = (t + 2 < 64 ? t + 2 : 63) * 64;
    const int kN1 = (t + 3 < 64 ? t + 3 : 63) * 64;

    rdA(0); rdB0(0);
    stA(3, 1, kA1);
    BARRIER(); LGKM0();
    __builtin_amdgcn_s_setprio(1); MFMA_Q(0, 0, b0); __builtin_amdgcn_s_setprio(0);
    BARRIER();

    rdB1(1);
    stB(0, 0, kN0);
    BARRIER(); LGKM0();
    __builtin_amdgcn_s_setprio(1); MFMA_Q(0, 1, b1); __builtin_amdgcn_s_setprio(0);
    VMCNT(10);
    BARRIER();

    rdA(1);
    stB(1, 1, kN0);
    BARRIER(); LGKM0();
    __builtin_amdgcn_s_setprio(1); MFMA_Q(1, 0, b0); __builtin_amdgcn_s_setprio(0);
    BARRIER();

    stA(0, 0, kN0);
    BARRIER(); LGKM0();
    __builtin_amdgcn_s_setprio(1); MFMA_Q(1, 1, b1); __builtin_amdgcn_s_setprio(0);
    VMCNT(8);
    BARRIER();

    rdA(2); rdB0(2);
    stA(1, 1, kN0);
    BARRIER(); LGKM0();
    __builtin_amdgcn_s_setprio(1); MFMA_Q(0, 0, b0); __builtin_amdgcn_s_setprio(0);
    BARRIER();

    rdB1(3);
    stB(2, 0, kN1);
    BARRIER(); LGKM0();
    __builtin_amdgcn_s_setprio(1); MFMA_Q(0, 1, b1); __builtin_amdgcn_s_setprio(0);
    VMCNT(10);
    BARRIER();

    rdA(3);
    stB(3, 1, kN1);
    BARRIER(); LGKM0();
    __builtin_amdgcn_s_setprio(1); MFMA_Q(1, 0, b0); __builtin_amdgcn_s_setprio(0);
    BARRIER();

    stA(2, 0, kN1);
    BARRIER(); LGKM0();
    __builtin_amdgcn_s_setprio(1); MFMA_Q(1, 1, b1); __builtin_amdgcn_s_setprio(0);
    VMCNT(8);
    BARRIER();
  }

  // epilogue: write fp32 partial for this split
  float* pp = part + (size_t)sp * NTOK * HDIM;
#pragma unroll
  for (int ai = 0; ai < 8; ++ai) {
    const int mh = ai >> 2, mm = ai & 3;
#pragma unroll
    for (int bj = 0; bj < 4; ++bj) {
      const int nh = bj >> 1, nn = bj & 1;
      const int col = col0 + wc * 64 + nh * 32 + nn * 16 + rrow;
#pragma unroll
      for (int r = 0; r < 4; ++r) {
        const int row = row0 + wr * 128 + mh * 64 + mm * 16 + klane * 4 + r;
        pp[(size_t)row * HDIM + col] = acc[ai][bj][r];
      }
    }
  }
}

// ---------------- reduce: out = sum_splits partial + sum_e rw*down_bias ----------------
__global__ __launch_bounds__(256) void k_reduce(const float* __restrict__ part,
                                                const float* __restrict__ dbias,
                                                const float* __restrict__ rw,
                                                float* __restrict__ out) {
  const int i = blockIdx.x * 256 + threadIdx.x;   // float4 index
  const int i4 = i * 4;
  const int n = i4 >> 11;          // token
  const int h = i4 & 2047;
  const size_t MSZ = (size_t)NTOK * HDIM / 4;
  const float4* p = (const float4*)part;
  float4 v0 = p[i];
  float4 v1 = p[i + MSZ];
  float4 v2 = p[i + 2 * MSZ];
  float4 v3 = p[i + 3 * MSZ];
  float4 s;
  s.x = (v0.x + v1.x) + (v2.x + v3.x);
  s.y = (v0.y + v1.y) + (v2.y + v3.y);
  s.z = (v0.z + v1.z) + (v2.z + v3.z);
  s.w = (v0.w + v1.w) + (v2.w + v3.w);
#pragma unroll
  for (int e = 0; e < NEXP; ++e) {
    float rwe = rw[n * NEXP + e];
    float4 db = *(const float4*)&dbias[(size_t)e * HDIM + h];
    s.x += rwe * db.x; s.y += rwe * db.y;
    s.z += rwe * db.z; s.w += rwe * db.w;
  }
  *(float4*)&out[i4] = s;
}

extern "C" void kernel_launch(void* const* d_in, const int* in_sizes, int n_in,
                              void* d_out, int out_size, void* d_ws, size_t ws_size,
                              hipStream_t stream) {
  const float* hs   = (const float*)d_in[0];
  const float* rw   = (const float*)d_in[1];
  const float* gup  = (const float*)d_in[2];
  const float* gupb = (const float*)d_in[3];
  const float* dwn  = (const float*)d_in[4];
  const float* dwnb = (const float*)d_in[5];
  float* out = (float*)d_out;

  u16* xbf   = (u16*)d_ws;
  u16* w1t   = xbf + (size_t)NTOK * HDIM;
  u16* w2t   = w1t + (size_t)NEXP * I2 * HDIM;
  u16* inter = w2t + (size_t)NEXP * HDIM * IDIM;
  // split-K partials (4 x 16 MB fp32) reuse the w1t region (dead after gemm1)
  float* part = (float*)w1t;
  size_t need = ((size_t)NTOK * HDIM + (size_t)NEXP * I2 * HDIM +
                 (size_t)NEXP * HDIM * IDIM + (size_t)NEXP * NTOK * IDIM) * 2;
  if (ws_size < need) return;

  k_cvt<<<(NTOK * HDIM) / (256 * 8), 256, 0, stream>>>(hs, xbf);

  dim3 g1(I2 / 32, HDIM / 32, NEXP);
  k_tc<<<g1, 256, 0, stream>>>(gup, w1t, HDIM, I2);
  dim3 g2(HDIM / 32, IDIM / 32, NEXP);
  k_tc<<<g2, 256, 0, stream>>>(dwn, w2t, IDIM, HDIM);

  k_gemm1<<<dim3(1024), 512, 0, stream>>>(xbf, w1t, gupb, rw, inter);

  k_gemm2<<<dim3(256), 512, 0, stream>>>(inter, w2t, part);

  k_reduce<<<dim3(NTOK * HDIM / 1024), 256, 0, stream>>>(part, dwnb, rw, out);
}

// Round 5
// 563.327 us; speedup vs baseline: 1.5200x; 1.0033x over previous
//
#include <hip/hip_runtime.h>
#include <cstdint>
#include <cstddef>

#define ALPHA 1.702f
#define LIMIT 7.0f

#define NTOK 2048
#define HDIM 2048
#define IDIM 2048
#define I2   4096
#define NEXP 8

typedef float f32x4 __attribute__((ext_vector_type(4)));
typedef short bf16x8 __attribute__((ext_vector_type(8)));
typedef unsigned short u16;

__device__ __forceinline__ u16 f2bf(float f) {
  unsigned u = __float_as_uint(f);
  u += 0x7fffu + ((u >> 16) & 1u);   // RNE
  return (u16)(u >> 16);
}

__device__ __forceinline__ void gload_lds16(const void* g, void* l) {
  __builtin_amdgcn_global_load_lds(
      (const __attribute__((address_space(1))) void*)g,
      (__attribute__((address_space(3))) void*)l, 16, 0, 0);
}

// Compiler-fenced barrier WITHOUT sched_barrier(0): plain-C++ ds_reads are
// compiler-tracked, so let it emit fine-grained lgkmcnt into the MFMA cluster
// (m97 behavior; m141 showed full pinning costs ~40%).
#define BARRIER() do { asm volatile("" ::: "memory"); __builtin_amdgcn_s_barrier(); asm volatile("" ::: "memory"); } while (0)
#define VMCNT(n)  asm volatile("s_waitcnt vmcnt(" #n ")" ::: "memory")

// ---------------- x: fp32 -> bf16 ----------------
__global__ __launch_bounds__(256) void k_cvt(const float* __restrict__ in,
                                             u16* __restrict__ out) {
  int i = blockIdx.x * blockDim.x + threadIdx.x;
  const float4* p = (const float4*)in + (size_t)i * 2;
  float4 a = p[0], b = p[1];
  union { u16 s[8]; uint4 v; } o;
  o.s[0] = f2bf(a.x); o.s[1] = f2bf(a.y); o.s[2] = f2bf(a.z); o.s[3] = f2bf(a.w);
  o.s[4] = f2bf(b.x); o.s[5] = f2bf(b.y); o.s[6] = f2bf(b.z); o.s[7] = f2bf(b.w);
  ((uint4*)out)[i] = o.v;
}

// ------------- transpose + convert: (R,C) fp32 -> (C,R) bf16 (verified 32x32) -------------
__global__ __launch_bounds__(256) void k_tc(const float* __restrict__ in,
                                            u16* __restrict__ out, int R, int C) {
  __shared__ float tile[32][33];
  const size_t mo = (size_t)blockIdx.z * R * C;
  const float* ip = in + mo;
  u16* op = out + mo;
  int c0 = blockIdx.x * 32, r0 = blockIdx.y * 32;
  int t = threadIdx.x;
  int tr = t >> 3, tc = (t & 7) * 4;
  float4 v = *(const float4*)&ip[(size_t)(r0 + tr) * C + c0 + tc];
  tile[tr][tc] = v.x; tile[tr][tc + 1] = v.y;
  tile[tr][tc + 2] = v.z; tile[tr][tc + 3] = v.w;
  __syncthreads();
  ushort4 o;
  o.x = f2bf(tile[tc + 0][tr]);
  o.y = f2bf(tile[tc + 1][tr]);
  o.z = f2bf(tile[tc + 2][tr]);
  o.w = f2bf(tile[tc + 3][tr]);
  *(ushort4*)&op[(size_t)(c0 + tr) * R + r0 + tc] = o;
}

// ======================= 256x256 8-wave 8-phase GEMM core =======================
#define MFMA_Q(mh, nh, bb) \
  _Pragma("unroll") for (int mm = 0; mm < 4; ++mm) \
  _Pragma("unroll") for (int nn = 0; nn < 2; ++nn) \
  _Pragma("unroll") for (int ks = 0; ks < 2; ++ks) \
    acc[(mh)*4+mm][(nh)*2+nn] = __builtin_amdgcn_mfma_f32_16x16x32_bf16( \
        a[mm][ks], (bb)[nn][ks], acc[(mh)*4+mm][(nh)*2+nn], 0, 0, 0);

// ---------------- GEMM1: gate_up + activation + rw fold ----------------
__global__ __launch_bounds__(512, 2) void k_gemm1(const u16* __restrict__ xbf,
                                                  const u16* __restrict__ w1t,
                                                  const float* __restrict__ gub,
                                                  const float* __restrict__ rw,
                                                  u16* __restrict__ inter) {
  __shared__ __align__(16) u16 Als[4][128 * 64];
  __shared__ __align__(16) u16 Bls[4][128 * 64];

  const int bid = (int)blockIdx.x;
  const int L = (bid & 7) * 128 + (bid >> 3);
  const int mtile = L & 7, ntile = (L >> 3) & 15, e = L >> 7;
  const int row0 = mtile * 256, col0 = ntile * 256;
  const u16* A = xbf;
  const u16* B = w1t + (size_t)e * I2 * HDIM;

  const int tid = threadIdx.x;
  const int w = tid >> 6, lane = tid & 63;
  const int wr = w >> 2, wc = w & 3;
  const int rrow = lane & 15, klane = lane >> 4;
  const int sA = (wr * 64 + rrow) * 64;
  const int sB = (wc * 32 + rrow) * 64;
  int kofs[2];
  kofs[0] = ((klane ^ (rrow & 7)) << 3);
  kofs[1] = (((4 + klane) ^ (rrow & 7)) << 3);

  auto stA = [&](int reg, int h, int k0) {
#pragma unroll
    for (int j = 0; j < 2; ++j) {
      int c = (w * 2 + j) * 64 + lane;
      int r = c >> 3, gg = c & 7;
      int ksw = ((gg ^ (r & 7)) << 3);
      int R = ((r >> 6) << 7) + h * 64 + (r & 63);
      gload_lds16(A + (size_t)(row0 + R) * HDIM + k0 + ksw,
                  &Als[reg][(size_t)(w * 2 + j) * 512]);
    }
  };
  auto stB = [&](int reg, int h, int k0) {
#pragma unroll
    for (int j = 0; j < 2; ++j) {
      int c = (w * 2 + j) * 64 + lane;
      int r = c >> 3, gg = c & 7;
      int ksw = ((gg ^ (r & 7)) << 3);
      int C = ((r >> 5) << 6) + h * 32 + (r & 31);
      gload_lds16(B + (size_t)(col0 + C) * HDIM + k0 + ksw,
                  &Bls[reg][(size_t)(w * 2 + j) * 512]);
    }
  };

  f32x4 acc[8][4];
#pragma unroll
  for (int i = 0; i < 8; ++i)
#pragma unroll
    for (int j = 0; j < 4; ++j) acc[i][j] = (f32x4){0.f, 0.f, 0.f, 0.f};

  bf16x8 a[4][2], b0[2][2], b1[2][2];
  auto rdA = [&](int reg) {
#pragma unroll
    for (int mm = 0; mm < 4; ++mm)
#pragma unroll
      for (int ks = 0; ks < 2; ++ks)
        a[mm][ks] = *(const bf16x8*)&Als[reg][sA + mm * 1024 + kofs[ks]];
  };
  auto rdB0 = [&](int reg) {
#pragma unroll
    for (int nn = 0; nn < 2; ++nn)
#pragma unroll
      for (int ks = 0; ks < 2; ++ks)
        b0[nn][ks] = *(const bf16x8*)&Bls[reg][sB + nn * 1024 + kofs[ks]];
  };
  auto rdB1 = [&](int reg) {
#pragma unroll
    for (int nn = 0; nn < 2; ++nn)
#pragma unroll
      for (int ks = 0; ks < 2; ++ks)
        b1[nn][ks] = *(const bf16x8*)&Bls[reg][sB + nn * 1024 + kofs[ks]];
  };

  stB(0, 0, 0); stB(1, 1, 0); stA(0, 0, 0); stA(1, 1, 0);
  stB(2, 0, 64); stB(3, 1, 64); stA(2, 0, 64);
  VMCNT(8);
  BARRIER();

  for (int i = 0; i < 16; ++i) {
    const int t = 2 * i;
    const int kA1 = (t + 1) * 64;
    const int kN0 = (t + 2 < 32 ? t + 2 : 31) * 64;
    const int kN1 = (t + 3 < 32 ? t + 3 : 31) * 64;

    rdA(0); rdB0(0);
    stA(3, 1, kA1);
    BARRIER();
    __builtin_amdgcn_s_setprio(1); MFMA_Q(0, 0, b0); __builtin_amdgcn_s_setprio(0);
    BARRIER();

    rdB1(1);
    stB(0, 0, kN0);
    BARRIER();
    __builtin_amdgcn_s_setprio(1); MFMA_Q(0, 1, b1); __builtin_amdgcn_s_setprio(0);
    VMCNT(10);
    BARRIER();

    rdA(1);
    stB(1, 1, kN0);
    BARRIER();
    __builtin_amdgcn_s_setprio(1); MFMA_Q(1, 0, b0); __builtin_amdgcn_s_setprio(0);
    BARRIER();

    stA(0, 0, kN0);
    BARRIER();
    __builtin_amdgcn_s_setprio(1); MFMA_Q(1, 1, b1); __builtin_amdgcn_s_setprio(0);
    VMCNT(8);
    BARRIER();

    rdA(2); rdB0(2);
    stA(1, 1, kN0);
    BARRIER();
    __builtin_amdgcn_s_setprio(1); MFMA_Q(0, 0, b0); __builtin_amdgcn_s_setprio(0);
    BARRIER();

    rdB1(3);
    stB(2, 0, kN1);
    BARRIER();
    __builtin_amdgcn_s_setprio(1); MFMA_Q(0, 1, b1); __builtin_amdgcn_s_setprio(0);
    VMCNT(10);
    BARRIER();

    rdA(3);
    stB(3, 1, kN1);
    BARRIER();
    __builtin_amdgcn_s_setprio(1); MFMA_Q(1, 0, b0); __builtin_amdgcn_s_setprio(0);
    BARRIER();

    stA(2, 0, kN1);
    BARRIER();
    __builtin_amdgcn_s_setprio(1); MFMA_Q(1, 1, b1); __builtin_amdgcn_s_setprio(0);
    VMCNT(8);
    BARRIER();
  }

  const float* bias = gub + (size_t)e * I2;
  u16* ip = inter + (size_t)e * NTOK * IDIM;
#pragma unroll
  for (int ai = 0; ai < 8; ++ai) {
    const int mh = ai >> 2, mm = ai & 3;
#pragma unroll
    for (int bj = 0; bj < 4; ++bj) {
      const int nh = bj >> 1, nn = bj & 1;
      const int col = col0 + wc * 64 + nh * 32 + nn * 16 + rrow;
      const float bv = bias[col];
#pragma unroll
      for (int r = 0; r < 4; ++r) {
        const int row = row0 + wr * 128 + mh * 64 + mm * 16 + klane * 4 + r;
        float gu = acc[ai][bj][r] + bv;
        float pg = __shfl_xor(gu, 1);
        float gate = (lane & 1) ? pg : gu;
        float up   = (lane & 1) ? gu : pg;
        gate = fminf(gate, LIMIT);
        up = fminf(fmaxf(up, -LIMIT), LIMIT);
        float glu = gate / (1.f + __expf(-ALPHA * gate));
        float val = (up + 1.f) * glu * rw[row * NEXP + e];
        if (!(lane & 1)) ip[(size_t)row * IDIM + (col >> 1)] = f2bf(val);
      }
    }
  }
}

// ---------------- GEMM2: 256x256 8-phase, split-K=4 (2 experts per split) ----------------
__global__ __launch_bounds__(512, 2) void k_gemm2(const u16* __restrict__ inter,
                                                  const u16* __restrict__ w2t,
                                                  float* __restrict__ part) {
  __shared__ __align__(16) u16 Als[4][128 * 64];
  __shared__ __align__(16) u16 Bls[4][128 * 64];

  const int bid = (int)blockIdx.x;
  const int L = (bid & 7) * 32 + (bid >> 3);
  const int mtile = L & 7, ntile = (L >> 3) & 7, sp = L >> 6;
  const int row0 = mtile * 256, col0 = ntile * 256;
  const int es = sp * 2;

  const int tid = threadIdx.x;
  const int w = tid >> 6, lane = tid & 63;
  const int wr = w >> 2, wc = w & 3;
  const int rrow = lane & 15, klane = lane >> 4;
  const int sA = (wr * 64 + rrow) * 64;
  const int sB = (wc * 32 + rrow) * 64;
  int kofs[2];
  kofs[0] = ((klane ^ (rrow & 7)) << 3);
  kofs[1] = (((4 + klane) ^ (rrow & 7)) << 3);

  auto stA = [&](int reg, int h, int k0) {
    const u16* Ab = inter + (size_t)(es + (k0 >> 11)) * NTOK * IDIM;
    const int kk = k0 & 2047;
#pragma unroll
    for (int j = 0; j < 2; ++j) {
      int c = (w * 2 + j) * 64 + lane;
      int r = c >> 3, gg = c & 7;
      int ksw = ((gg ^ (r & 7)) << 3);
      int R = ((r >> 6) << 7) + h * 64 + (r & 63);
      gload_lds16(Ab + (size_t)(row0 + R) * IDIM + kk + ksw,
                  &Als[reg][(size_t)(w * 2 + j) * 512]);
    }
  };
  auto stB = [&](int reg, int h, int k0) {
    const u16* Bb = w2t + (size_t)(es + (k0 >> 11)) * HDIM * IDIM;
    const int kk = k0 & 2047;
#pragma unroll
    for (int j = 0; j < 2; ++j) {
      int c = (w * 2 + j) * 64 + lane;
      int r = c >> 3, gg = c & 7;
      int ksw = ((gg ^ (r & 7)) << 3);
      int C = ((r >> 5) << 6) + h * 32 + (r & 31);
      gload_lds16(Bb + (size_t)(col0 + C) * IDIM + kk + ksw,
                  &Bls[reg][(size_t)(w * 2 + j) * 512]);
    }
  };

  f32x4 acc[8][4];
#pragma unroll
  for (int i = 0; i < 8; ++i)
#pragma unroll
    for (int j = 0; j < 4; ++j) acc[i][j] = (f32x4){0.f, 0.f, 0.f, 0.f};

  bf16x8 a[4][2], b0[2][2], b1[2][2];
  auto rdA = [&](int reg) {
#pragma unroll
    for (int mm = 0; mm < 4; ++mm)
#pragma unroll
      for (int ks = 0; ks < 2; ++ks)
        a[mm][ks] = *(const bf16x8*)&Als[reg][sA + mm * 1024 + kofs[ks]];
  };
  auto rdB0 = [&](int reg) {
#pragma unroll
    for (int nn = 0; nn < 2; ++nn)
#pragma unroll
      for (int ks = 0; ks < 2; ++ks)
        b0[nn][ks] = *(const bf16x8*)&Bls[reg][sB + nn * 1024 + kofs[ks]];
  };
  auto rdB1 = [&](int reg) {
#pragma unroll
    for (int nn = 0; nn < 2; ++nn)
#pragma unroll
      for (int ks = 0; ks < 2; ++ks)
        b1[nn][ks] = *(const bf16x8*)&Bls[reg][sB + nn * 1024 + kofs[ks]];
  };

  stB(0, 0, 0); stB(1, 1, 0); stA(0, 0, 0); stA(1, 1, 0);
  stB(2, 0, 64); stB(3, 1, 64); stA(2, 0, 64);
  VMCNT(8);
  BARRIER();

  for (int i = 0; i < 32; ++i) {               // 64 K-tiles, 2 per iter
    const int t = 2 * i;
    const int kA1 = (t + 1) * 64;
    const int kN0 = (t + 2 < 64 ? t + 2 : 63) * 64;
    const int kN1 = (t + 3 < 64 ? t + 3 : 63) * 64;

    rdA(0); rdB0(0);
    stA(3, 1, kA1);
    BARRIER();
    __builtin_amdgcn_s_setprio(1); MFMA_Q(0, 0, b0); __builtin_amdgcn_s_setprio(0);
    BARRIER();

    rdB1(1);
    stB(0, 0, kN0);
    BARRIER();
    __builtin_amdgcn_s_setprio(1); MFMA_Q(0, 1, b1); __builtin_amdgcn_s_setprio(0);
    VMCNT(10);
    BARRIER();

    rdA(1);
    stB(1, 1, kN0);
    BARRIER();
    __builtin_amdgcn_s_setprio(1); MFMA_Q(1, 0, b0); __builtin_amdgcn_s_setprio(0);
    BARRIER();

    stA(0, 0, kN0);
    BARRIER();
    __builtin_amdgcn_s_setprio(1); MFMA_Q(1, 1, b1); __builtin_amdgcn_s_setprio(0);
    VMCNT(8);
    BARRIER();

    rdA(2); rdB0(2);
    stA(1, 1, kN0);
    BARRIER();
    __builtin_amdgcn_s_setprio(1); MFMA_Q(0, 0, b0); __builtin_amdgcn_s_setprio(0);
    BARRIER();

    rdB1(3);
    stB(2, 0, kN1);
    BARRIER();
    __builtin_amdgcn_s_setprio(1); MFMA_Q(0, 1, b1); __builtin_amdgcn_s_setprio(0);
    VMCNT(10);
    BARRIER();

    rdA(3);
    stB(3, 1, kN1);
    BARRIER();
    __builtin_amdgcn_s_setprio(1); MFMA_Q(1, 0, b0); __builtin_amdgcn_s_setprio(0);
    BARRIER();

    stA(2, 0, kN1);
    BARRIER();
    __builtin_amdgcn_s_setprio(1); MFMA_Q(1, 1, b1); __builtin_amdgcn_s_setprio(0);
    VMCNT(8);
    BARRIER();
  }

  float* pp = part + (size_t)sp * NTOK * HDIM;
#pragma unroll
  for (int ai = 0; ai < 8; ++ai) {
    const int mh = ai >> 2, mm = ai & 3;
#pragma unroll
    for (int bj = 0; bj < 4; ++bj) {
      const int nh = bj >> 1, nn = bj & 1;
      const int col = col0 + wc * 64 + nh * 32 + nn * 16 + rrow;
#pragma unroll
      for (int r = 0; r < 4; ++r) {
        const int row = row0 + wr * 128 + mh * 64 + mm * 16 + klane * 4 + r;
        pp[(size_t)row * HDIM + col] = acc[ai][bj][r];
      }
    }
  }
}

// ---------------- reduce: out = sum_splits partial + sum_e rw*down_bias ----------------
__global__ __launch_bounds__(256) void k_reduce(const float* __restrict__ part,
                                                const float* __restrict__ dbias,
                                                const float* __restrict__ rw,
                                                float* __restrict__ out) {
  const int i = blockIdx.x * 256 + threadIdx.x;
  const int i4 = i * 4;
  const int n = i4 >> 11;
  const int h = i4 & 2047;
  const size_t MSZ = (size_t)NTOK * HDIM / 4;
  const float4* p = (const float4*)part;
  float4 v0 = p[i];
  float4 v1 = p[i + MSZ];
  float4 v2 = p[i + 2 * MSZ];
  float4 v3 = p[i + 3 * MSZ];
  float4 s;
  s.x = (v0.x + v1.x) + (v2.x + v3.x);
  s.y = (v0.y + v1.y) + (v2.y + v3.y);
  s.z = (v0.z + v1.z) + (v2.z + v3.z);
  s.w = (v0.w + v1.w) + (v2.w + v3.w);
#pragma unroll
  for (int e = 0; e < NEXP; ++e) {
    float rwe = rw[n * NEXP + e];
    float4 db = *(const float4*)&dbias[(size_t)e * HDIM + h];
    s.x += rwe * db.x; s.y += rwe * db.y;
    s.z += rwe * db.z; s.w += rwe * db.w;
  }
  *(float4*)&out[i4] = s;
}

extern "C" void kernel_launch(void* const* d_in, const int* in_sizes, int n_in,
                              void* d_out, int out_size, void* d_ws, size_t ws_size,
                              hipStream_t stream) {
  const float* hs   = (const float*)d_in[0];
  const float* rw   = (const float*)d_in[1];
  const float* gup  = (const float*)d_in[2];
  const float* gupb = (const float*)d_in[3];
  const float* dwn  = (const float*)d_in[4];
  const float* dwnb = (const float*)d_in[5];
  float* out = (float*)d_out;

  u16* xbf   = (u16*)d_ws;
  u16* w1t   = xbf + (size_t)NTOK * HDIM;
  u16* w2t   = w1t + (size_t)NEXP * I2 * HDIM;
  u16* inter = w2t + (size_t)NEXP * HDIM * IDIM;
  float* part = (float*)w1t;
  size_t need = ((size_t)NTOK * HDIM + (size_t)NEXP * I2 * HDIM +
                 (size_t)NEXP * HDIM * IDIM + (size_t)NEXP * NTOK * IDIM) * 2;
  if (ws_size < need) return;

  k_cvt<<<(NTOK * HDIM) / (256 * 8), 256, 0, stream>>>(hs, xbf);

  dim3 g1(I2 / 32, HDIM / 32, NEXP);
  k_tc<<<g1, 256, 0, stream>>>(gup, w1t, HDIM, I2);
  dim3 g2(HDIM / 32, IDIM / 32, NEXP);
  k_tc<<<g2, 256, 0, stream>>>(dwn, w2t, IDIM, HDIM);

  k_gemm1<<<dim3(1024), 512, 0, stream>>>(xbf, w1t, gupb, rw, inter);

  k_gemm2<<<dim3(256), 512, 0, stream>>>(inter, w2t, part);

  k_reduce<<<dim3(NTOK * HDIM / 1024), 256, 0, stream>>>(part, dwnb, rw, out);
}